// Round 8
// baseline (148.841 us; speedup 1.0000x reference)
//
#include <hip/hip_runtime.h>
#include <hip/hip_bf16.h>
#include <stdint.h>

#define NB 4
#define NT 4096
#define NE 100
#define ND 64

typedef __attribute__((ext_vector_type(8))) short short8;
typedef __attribute__((ext_vector_type(4))) short short4_;
typedef __attribute__((ext_vector_type(4))) float float4_;
typedef unsigned short ushort_t;

__device__ __forceinline__ unsigned short f2bf(float f) {
  union { float f; uint32_t u; } v; v.f = f;
  uint32_t u = v.u;
  u += 0x7fffu + ((u >> 16) & 1u);   // RNE
  return (unsigned short)(u >> 16);
}

__device__ __forceinline__ float bf2f(short us) {
  union { uint32_t u; float f; } v;
  v.u = ((uint32_t)(unsigned short)us) << 16;
  return v.f;
}

__device__ __forceinline__ float fast_exp2(float x) {
#if __has_builtin(__builtin_amdgcn_exp2f)
  return __builtin_amdgcn_exp2f(x);
#else
  return exp2f(x);
#endif
}

// ---------------- projection ----------------
// 256 blocks x 256 thr, 64 rows/block. q = (x@Wq)*0.125*log2e, k = x@Wk,
// v^T via LDS transpose with 128B-contiguous per-d writes. W staged once
// per block into LDS bf16.
__global__ __launch_bounds__(256) void proj_kernel(
    const float* __restrict__ x, const float* __restrict__ Wq,
    const float* __restrict__ Wk, const float* __restrict__ Wv,
    ushort_t* __restrict__ Qb, ushort_t* __restrict__ Kb,
    ushort_t* __restrict__ Vt) {
  __shared__ __align__(16) float xs[64 * NE];          // 25.6 KB
  __shared__ __align__(16) ushort_t Wl[3][25][64][4];  // 38.4 KB
  __shared__ __align__(16) ushort_t Vl[64][72];        // 9.2 KB

  const int tid = threadIdx.x;
  const int r0  = blockIdx.x * 64;

  { // stage x[64][100] -> LDS, coalesced
    const float4_* xsrc = (const float4_*)(x + (size_t)r0 * NE);
    float4_* xdst = (float4_*)xs;
    for (int i = tid; i < 1600; i += 256) xdst[i] = xsrc[i];
  }
  { // stage W[3][100][64] -> LDS bf16, e-quad-major
    const int ch = tid >> 6, d = tid & 63;
    if (ch < 3) {
      const float* Ws = (ch == 0) ? Wq : (ch == 1) ? Wk : Wv;
      #pragma unroll 5
      for (int qd = 0; qd < 25; ++qd) {
        short4_ pk;
        #pragma unroll
        for (int jj = 0; jj < 4; ++jj)
          pk[jj] = (short)f2bf(Ws[(4*qd + jj)*ND + d]);
        *(short4_*)&Wl[ch][qd][d][0] = pk;
      }
    }
  }
  __syncthreads();

  const int wv = tid >> 6, lane = tid & 63;
  const float QS = 0.125f * 1.44269504088896340736f; // scale * log2(e)

  for (int it = 0; it < 4; ++it) {
    float aq[4] = {0,0,0,0}, ak[4] = {0,0,0,0}, av[4] = {0,0,0,0};
    const float* xw = xs + (it*16 + wv*4) * NE;
    for (int qd = 0; qd < 25; ++qd) {
      short4_ w4q = *(const short4_*)&Wl[0][qd][lane][0];
      short4_ w4k = *(const short4_*)&Wl[1][qd][lane][0];
      short4_ w4v = *(const short4_*)&Wl[2][qd][lane][0];
      float4_ x0 = *(const float4_*)&xw[0*NE + 4*qd];
      float4_ x1 = *(const float4_*)&xw[1*NE + 4*qd];
      float4_ x2 = *(const float4_*)&xw[2*NE + 4*qd];
      float4_ x3 = *(const float4_*)&xw[3*NE + 4*qd];
      #pragma unroll
      for (int jj = 0; jj < 4; ++jj) {
        float fq = bf2f(w4q[jj]), fk = bf2f(w4k[jj]), fv = bf2f(w4v[jj]);
        aq[0] += x0[jj]*fq; ak[0] += x0[jj]*fk; av[0] += x0[jj]*fv;
        aq[1] += x1[jj]*fq; ak[1] += x1[jj]*fk; av[1] += x1[jj]*fv;
        aq[2] += x2[jj]*fq; ak[2] += x2[jj]*fk; av[2] += x2[jj]*fv;
        aq[3] += x3[jj]*fq; ak[3] += x3[jj]*fk; av[3] += x3[jj]*fv;
      }
    }
    #pragma unroll
    for (int j = 0; j < 4; ++j) {
      int lrow = it*16 + wv*4 + j;
      int row  = r0 + lrow;
      Qb[(size_t)row*ND + lane] = f2bf(aq[j] * QS);
      Kb[(size_t)row*ND + lane] = f2bf(ak[j]);
      Vl[lrow][lane] = f2bf(av[j]);
    }
  }
  __syncthreads();

  { // transposed V write: per d, 64 t-values = 128B contiguous
    const int b = r0 >> 12, r0t = r0 & (NT - 1);
    for (int i = tid; i < 512; i += 256) {
      int d = i >> 3, seg = i & 7;
      short8 pk;
      #pragma unroll
      for (int k2 = 0; k2 < 8; ++k2) pk[k2] = (short)Vl[seg*8 + k2][d];
      *(short8*)(Vt + ((size_t)(b*ND + d))*NT + r0t + seg*8) = pk;
    }
  }
}

// ---------------- causal flash attention ----------------
// 256 blocks x 512 thr (8 fully-independent waves), 1 block/CU, XCD-mapped
// (blk&7 = xcd, batch = xcd>>1 -> K/Vt L2-resident per XCD; FETCH ~5MB R6).
// Block owns q-group pair (127-p, p). Wave w = (pp = w>>1 kv-stride-slot,
// h = w&1 q-half of 16 rows). NO LDS staging, NO main-loop barriers:
// K/V fragments loaded straight from L2-hot global (R1-proven pattern),
// next-K register-double-buffered. Per-lane partial lsum (cross-lane sum
// deferred to epilogue); m kept row-uniform on the rare rescale path only.
// Per-pair (m,l,O) partials combined in-LDS at phase end.
__global__ __launch_bounds__(512, 2) void attn_kernel(
    const ushort_t* __restrict__ Qb, const ushort_t* __restrict__ Kb,
    const ushort_t* __restrict__ Vt, float* __restrict__ out) {
  __shared__ __align__(16) ushort_t Pb[8][16][72];   // 18.4 KB per-wave P
  __shared__ __align__(16) float Om[8][16][64];      // 32 KB partials
  __shared__ float Ml[8][16][2];                     // 1 KB

  const int tid  = threadIdx.x;
  const int w    = tid >> 6, lane = tid & 63;
  const int pp   = w >> 1, h = w & 1;
  const int qrow = lane & 15, grp = lane >> 4;

  const int blk = blockIdx.x;
  const int xcd = blk & 7;
  const int b   = xcd >> 1;                       // batch pinned to XCD pair
  const int p   = ((blk >> 3) << 1) | (xcd & 1);  // pair id [0,64)

  const ushort_t* Kbase = Kb + (size_t)b*NT*ND;
  const ushort_t* Vtb   = Vt + (size_t)b*ND*NT;
  ushort_t* Pw = &Pb[w][0][0];

  for (int phase = 0; phase < 2; ++phase) {
    const int g  = phase ? p : (127 - p);
    const int q0 = g << 5;
    const int nt = (g >> 1) + 1;
    const int qglob = q0 + h*16 + qrow;

    const ushort_t* Qr = Qb + ((size_t)(b*NT + q0 + h*16 + qrow))*ND + 8*grp;
    const short8 qf0 = *(const short8*)(Qr);
    const short8 qf1 = *(const short8*)(Qr + 32);

    float4_ O0 = {0,0,0,0}, O1 = {0,0,0,0}, O2 = {0,0,0,0}, O3 = {0,0,0,0};
    float m = -1e30f, lsum = 0.f;   // lsum = per-lane PARTIAL row sum
    short8 kc[8], kn[8];

    const int maxIter = (nt + 3) >> 2;

    if (pp < nt) { // prologue: K fragments of tile pp straight from global
      const int kv0 = pp << 6;
      #pragma unroll
      for (int st = 0; st < 4; ++st) {
        const ushort_t* kp = Kbase + (size_t)(kv0 + st*16 + qrow)*ND + 8*grp;
        kc[2*st]   = *(const short8*)(kp);
        kc[2*st+1] = *(const short8*)(kp + 32);
      }
    }
    #pragma unroll
    for (int i = 0; i < 8; ++i) kn[i] = kc[i];

    for (int it = 0; it < maxIter; ++it) {
      const int t   = pp + (it << 2);
      const bool act = (t < nt);
      if (act) {
        const int kv0 = t << 6;

        // V fragments issued now, consumed after softmax (~600cy later)
        short8 vf[8];
        #pragma unroll
        for (int j = 0; j < 4; ++j) {
          const ushort_t* vp = Vtb + (size_t)(j*16 + qrow)*NT + kv0 + 8*grp;
          vf[2*j]   = *(const short8*)(vp);
          vf[2*j+1] = *(const short8*)(vp + 32);
        }
        // prefetch next K tile (consumed next iteration, ~1200cy away)
        if (t + 4 < nt) {
          const int kn0 = (t + 4) << 6;
          #pragma unroll
          for (int st = 0; st < 4; ++st) {
            const ushort_t* kp = Kbase + (size_t)(kn0 + st*16 + qrow)*ND + 8*grp;
            kn[2*st]   = *(const short8*)(kp);
            kn[2*st+1] = *(const short8*)(kp + 32);
          }
        }

        // S^T = K_tile . Q^T (lane owns q-row qglob; kv = kv0+st*16+grp*4+r)
        float4_ sA[4];
        #pragma unroll
        for (int st = 0; st < 4; ++st) {
          float4_ acc = {0,0,0,0};
          acc = __builtin_amdgcn_mfma_f32_16x16x32_bf16(kc[2*st],   qf0, acc, 0,0,0);
          acc = __builtin_amdgcn_mfma_f32_16x16x32_bf16(kc[2*st+1], qf1, acc, 0,0,0);
          sA[st] = acc;
        }

        if (t == nt - 1) { // only the diagonal tile violates causality
          #pragma unroll
          for (int st = 0; st < 4; ++st)
            #pragma unroll
            for (int r = 0; r < 4; ++r) {
              int kv = kv0 + st*16 + grp*4 + r;
              if (kv > qglob) sA[st][r] = -1e30f;
            }
        }

        // online softmax (log2 domain), defer-max THR=8.
        // m stays row-uniform (shfl only on rescale); lsum is per-lane partial.
        float pmax = sA[0][0];
        #pragma unroll
        for (int st = 0; st < 4; ++st)
          #pragma unroll
          for (int r = 0; r < 4; ++r) pmax = fmaxf(pmax, sA[st][r]);
        if (!__all(pmax <= m + 8.0f)) {
          float tm = pmax;
          tm = fmaxf(tm, __shfl_xor(tm, 16));
          tm = fmaxf(tm, __shfl_xor(tm, 32));
          const float mnew  = fmaxf(m, tm);
          const float alpha = fast_exp2(m - mnew);
          m = mnew;
          lsum *= alpha;
          #pragma unroll
          for (int r = 0; r < 4; ++r) {
            float ar = __shfl(alpha, grp*4 + r);
            O0[r] *= ar; O1[r] *= ar; O2[r] *= ar; O3[r] *= ar;
          }
        }

        float ps0 = 0.f, ps1 = 0.f;
        #pragma unroll
        for (int st = 0; st < 4; ++st) {
          short4_ pv;
          float pe0 = fast_exp2(sA[st][0] - m);
          float pe1 = fast_exp2(sA[st][1] - m);
          float pe2 = fast_exp2(sA[st][2] - m);
          float pe3 = fast_exp2(sA[st][3] - m);
          pv[0] = (short)f2bf(pe0); pv[1] = (short)f2bf(pe1);
          pv[2] = (short)f2bf(pe2); pv[3] = (short)f2bf(pe3);
          ps0 += pe0 + pe1; ps1 += pe2 + pe3;
          *(short4_*)&Pw[qrow*72 + st*16 + grp*4] = pv;
        }
        lsum += ps0 + ps1;

        asm volatile("s_waitcnt lgkmcnt(0)" ::: "memory");

        const short8 pf0 = *(const short8*)&Pw[qrow*72 + 8*grp];
        const short8 pf1 = *(const short8*)&Pw[qrow*72 + 32 + 8*grp];
        O0 = __builtin_amdgcn_mfma_f32_16x16x32_bf16(pf0, vf[0], O0, 0,0,0);
        O0 = __builtin_amdgcn_mfma_f32_16x16x32_bf16(pf1, vf[1], O0, 0,0,0);
        O1 = __builtin_amdgcn_mfma_f32_16x16x32_bf16(pf0, vf[2], O1, 0,0,0);
        O1 = __builtin_amdgcn_mfma_f32_16x16x32_bf16(pf1, vf[3], O1, 0,0,0);
        O2 = __builtin_amdgcn_mfma_f32_16x16x32_bf16(pf0, vf[4], O2, 0,0,0);
        O2 = __builtin_amdgcn_mfma_f32_16x16x32_bf16(pf1, vf[5], O2, 0,0,0);
        O3 = __builtin_amdgcn_mfma_f32_16x16x32_bf16(pf0, vf[6], O3, 0,0,0);
        O3 = __builtin_amdgcn_mfma_f32_16x16x32_bf16(pf1, vf[7], O3, 0,0,0);

        #pragma unroll
        for (int i = 0; i < 8; ++i) kc[i] = kn[i];
      }
    }

    // finalize per-lane partial lsum -> per-row sum (once per phase)
    lsum += __shfl_xor(lsum, 16);
    lsum += __shfl_xor(lsum, 32);

    // ---- per-wave partials (O rows are grp*4+r; cols j*16+qrow)
    #pragma unroll
    for (int r = 0; r < 4; ++r) {
      int row = grp*4 + r;
      Om[w][row][0*16 + qrow] = O0[r];
      Om[w][row][1*16 + qrow] = O1[r];
      Om[w][row][2*16 + qrow] = O2[r];
      Om[w][row][3*16 + qrow] = O3[r];
    }
    if (lane < 16) {
      Ml[w][lane][0] = m;
      Ml[w][lane][1] = lsum;
    }
    __syncthreads();

    // ---- combine the 4 kv-slice partials per q-half, normalize, store
    for (int i = tid; i < 2048; i += 512) {
      int row = i >> 6, d = i & 63;
      int hh = row >> 4, r16 = row & 15;
      float M = -3e30f;
      #pragma unroll
      for (int p2 = 0; p2 < 4; ++p2)
        M = fmaxf(M, Ml[2*p2 + hh][r16][0]);
      float ls = 0.f, os = 0.f;
      #pragma unroll
      for (int p2 = 0; p2 < 4; ++p2) {
        int w2 = 2*p2 + hh;
        float sc = fast_exp2(Ml[w2][r16][0] - M);
        ls += sc * Ml[w2][r16][1];
        os += sc * Om[w2][r16][d];
      }
      out[((size_t)b*NT + q0 + row)*ND + d] = os / ls;
    }
    __syncthreads();   // Om/Ml safe to reuse in next phase
  }
}

extern "C" void kernel_launch(void* const* d_in, const int* in_sizes, int n_in,
                              void* d_out, int out_size, void* d_ws, size_t ws_size,
                              hipStream_t stream) {
  const float* x  = (const float*)d_in[0];
  const float* Wq = (const float*)d_in[1];
  const float* Wk = (const float*)d_in[2];
  const float* Wv = (const float*)d_in[3];
  float* out = (float*)d_out;

  ushort_t* Qb = (ushort_t*)d_ws;                 // [B][T][64] bf16, 2 MB
  ushort_t* Kb = Qb + (size_t)NB*NT*ND;           // [B][T][64] bf16, 2 MB
  ushort_t* Vt = Kb + (size_t)NB*NT*ND;           // [B][64][T] bf16, 2 MB

  proj_kernel<<<dim3(256), dim3(256), 0, stream>>>(x, Wq, Wk, Wv, Qb, Kb, Vt);
  attn_kernel<<<dim3(256), dim3(512), 0, stream>>>(Qb, Kb, Vt, out);
}